// Round 9
// baseline (351.130 us; speedup 1.0000x reference)
//
#include <hip/hip_runtime.h>
#include <hip/hip_bf16.h>
#include <stdint.h>
#include <stddef.h>

// Causal single-head attention, B=4 S=2048 D=1024. fp32 in/out; bf16 MFMA inside.
// R16: back-half attack, GEMM core reverted to best-measured R14 (307.4us).
// (1) softmax kernel REMOVED: Sc diag-tiles mask above-diagonal with -1e30;
//     tiny row_stats kernel computes per-row {M, 1/Z}; PV applies
//     p = exp(s - M_row) inline on A-fragments and scales epilogue by invZ.
//     P buffer gone (saves 67MB softmax traffic + 8192-block dispatch).
// (2) PV (MODE 3) A-operand loaded DIRECT from global per-lane (row/k formula
//     identical to the LDS fragment map; 128B lines L1-re-read 8x/step),
//     halving PV's barrier-coupled async staging (B only).
// QKV and Sc GEMM paths byte-identical to R14 => QKV top-5 time is the control.

typedef __hip_bfloat16 bf16;
typedef short short8 __attribute__((ext_vector_type(8)));
typedef short short4v __attribute__((ext_vector_type(4)));
typedef float f32x4 __attribute__((ext_vector_type(4)));

#define BM 128
#define BN 128
#define BK 64
#define MSZ 8192   // B*S
#define DD 1024    // D

__device__ __forceinline__ void cstore(float* p, float v) { *p = v; }
__device__ __forceinline__ void cstore(bf16* p, float v) { *p = __float2bfloat16(v); }

// fp32 -> bf16 downcast, 4 elems/thread
__global__ __launch_bounds__(256)
void f2b(const float* __restrict__ s, bf16* __restrict__ d, int n) {
  const int i = (blockIdx.x * 256 + threadIdx.x) * 4;
  if (i >= n) return;
  const float4 v = *(const float4*)(s + i);
  bf16 t[4] = {__float2bfloat16(v.x), __float2bfloat16(v.y),
               __float2bfloat16(v.z), __float2bfloat16(v.w)};
  *(short4v*)(d + i) = *(short4v*)t;
}

// three weight matrices -> contiguous bf16 block [Wq;Wk;Wv]
__global__ __launch_bounds__(256)
void f2b3(const float* __restrict__ a, const float* __restrict__ b,
          const float* __restrict__ c, bf16* __restrict__ d, int n) {
  const float* s = (blockIdx.y == 0) ? a : (blockIdx.y == 1) ? b : c;
  const int i = (blockIdx.x * 256 + threadIdx.x) * 4;
  if (i >= n) return;
  const float4 v = *(const float4*)(s + i);
  bf16 t[4] = {__float2bfloat16(v.x), __float2bfloat16(v.y),
               __float2bfloat16(v.z), __float2bfloat16(v.w)};
  *(short4v*)(d + (size_t)blockIdx.y * n + i) = *(short4v*)t;
}

// C[M,N] = A[M,K] * B[N,K]^T (both K-contiguous), bf16 in. Inner loop = R8/R14.
// MODE 1: QKV — A=xb, B=W_all[3072,1024]; bx<16 -> Q|K rows, bx>=16 -> V
//         transposed into C2[D][MS].                         1536 blocks.
// MODE 2: Sc — triangular, XCD pair per batch; diagonal tiles write -1e30
//         above the diagonal (pre-masked for PV's inline exp). 544 blocks.
// MODE 3: PV — float out, K clipped at diagonal; A = Sc read DIRECT from
//         global per lane; p = exp(a - M_row); epilogue x invZ. 512 blocks.
//         C2 carries the {M, invZ} float2 buffer.
template <int MODE, typename CT>
__global__ __launch_bounds__(256, 4)
void gemm_bt(const bf16* __restrict__ A, const bf16* __restrict__ B,
             CT* __restrict__ C, bf16* __restrict__ C2,
             int lda, int ldb, int ldc, int K,
             long sA, long sB, long sC, float scale) {
  int by, bx, zb;
  const int flat = blockIdx.x;
  const int c = flat & 7, j = flat >> 3;  // XCD (flat%8 round-robin)
  if (MODE == 1) {
    // 1536 = 8 XCD x (24 bx x 8 by). A-band 2MB L2-resident; bx-outer.
    by = c * 8 + (j & 7);
    bx = j >> 3;
    zb = 0;
  } else if (MODE == 2) {
    // 544 = 8 XCD x 68. XCD pair owns batch; halves split tri range 0..135.
    zb = c >> 1;
    const int t = (c & 1) * 68 + j;
    by = (int)((__fsqrt_rn(8.f * (float)t + 1.f) - 1.f) * 0.5f);
    while ((by + 1) * (by + 2) / 2 <= t) by++;
    while (by * (by + 1) / 2 > t) by--;
    bx = t - by * (by + 1) / 2;
  } else {
    // 512 = 8 XCD x 64. XCD pair owns batch; bx-inner, by parity-desc.
    zb = c >> 1;
    bx = j & 7;
    by = 2 * (7 - (j >> 3)) + (c & 1);
  }

  __shared__ short8 As[1024];  // 16 KB: [rb 0..15][g 0..7][r8 0..7]
  __shared__ short8 Bs[1024];  // 16 KB

  const int tid = threadIdx.x;
  const int wave = tid >> 6, lane = tid & 63;
  const int wm = wave >> 1, wn = wave & 1;  // 2x2 wave grid, 64x64 each
  const int l15 = lane & 15, q4 = lane >> 4;
  const int bm0 = by * BM, bn0 = bx * BN;

  const bf16* Az = A + (long)zb * sA;
  const bf16* Bz = B + (long)zb * sB;
  CT* Cz = C + (long)zb * sC;
  const float2* mz = (const float2*)C2;  // MODE 3 only

  // staging coords: lane = (g<<3)|r8
  const int sg = lane >> 3, sr = lane & 7;
  const bf16* apg = Az + (size_t)(bm0 + wave * 32 + sr) * lda + sg * 8;
  const bf16* bpg = Bz + (size_t)(bn0 + wave * 32 + sr) * ldb + sg * 8;
  short8* asw = &As[wave * 256];  // 4 rowblocks * 64 short8 per wave
  short8* bsw = &Bs[wave * 256];

  const int Ke = (MODE == 3) ? min(K, (by + 1) * BM) : K;

  // fragment read bases: idx(row,gran) = (row>>3)*64 + gran*8 + (row&7)
  const int rh = l15 >> 3, r3 = l15 & 7;
  const int fra = wm * 512 + rh * 64 + q4 * 8 + r3;
  const int frb = wn * 512 + rh * 64 + q4 * 8 + r3;

  // MODE 3: direct A base (row = bm0+wm*64+i*16+l15, k = k0+s*32+q4*8) + M
  const bf16* adir = Az + (size_t)(bm0 + wm * 64 + l15) * lda + q4 * 8;
  float Mi[4];
  if (MODE == 3) {
#pragma unroll
    for (int i = 0; i < 4; i++)
      Mi[i] = mz[(size_t)zb * 2048 + bm0 + wm * 64 + i * 16 + l15].x;
  }

  f32x4 acc[4][4] = {};

  for (int k0 = 0; k0 < Ke; k0 += BK) {
    if (MODE != 3) {
#pragma unroll
      for (int jj = 0; jj < 4; jj++)
        __builtin_amdgcn_global_load_lds(apg + (size_t)jj * 8 * lda + k0,
                                         asw + jj * 64, 16, 0, 0);
    }
#pragma unroll
    for (int jj = 0; jj < 4; jj++)
      __builtin_amdgcn_global_load_lds(bpg + (size_t)jj * 8 * ldb + k0,
                                       bsw + jj * 64, 16, 0, 0);

    short8 ar0[4], ar1[4];
    if (MODE == 3) {
#pragma unroll
      for (int i = 0; i < 4; i++)
        ar0[i] = *(const short8*)(adir + (size_t)(i * 16) * lda + k0);
#pragma unroll
      for (int i = 0; i < 4; i++)
        ar1[i] = *(const short8*)(adir + (size_t)(i * 16) * lda + k0 + 32);
    }
    __syncthreads();  // drains vmcnt(0): B tile (and A if staged) resident

#pragma unroll
    for (int s = 0; s < 2; s++) {
      short8 af[4], bfr[4];
      if (MODE == 3) {
#pragma unroll
        for (int i = 0; i < 4; i++) {
          const short8 raw = (s == 0) ? ar0[i] : ar1[i];
#pragma unroll
          for (int e = 0; e < 8; e++) {
            const float f = __bfloat162float(((const bf16*)&raw)[e]);
            ((bf16*)&af[i])[e] = __float2bfloat16(__expf(f - Mi[i]));
          }
        }
      } else {
#pragma unroll
        for (int i = 0; i < 4; i++) af[i] = As[fra + i * 128 + s * 32];
      }
#pragma unroll
      for (int jj = 0; jj < 4; jj++) bfr[jj] = Bs[frb + jj * 128 + s * 32];
#pragma unroll
      for (int i = 0; i < 4; i++)
#pragma unroll
        for (int jj = 0; jj < 4; jj++)
          acc[i][jj] = __builtin_amdgcn_mfma_f32_16x16x32_bf16(af[i], bfr[jj], acc[i][jj], 0, 0, 0);
    }
    __syncthreads();  // LDS free for next stage
  }

  // epilogue: C/D layout col=lane&15, row=(lane>>4)*4+reg  [m89/m91 verified]
  if (MODE == 1 && bx >= 16) {
    // V block: write transposed into C2[D][MS]; pack r=0..3 (consec rows) 8 B
#pragma unroll
    for (int i = 0; i < 4; i++) {
#pragma unroll
      for (int jj = 0; jj < 4; jj++) {
        const int rowb = bm0 + wm * 64 + i * 16 + q4 * 4;
        const int v = (bn0 - 2048) + wn * 64 + jj * 16 + l15;
        bf16 t[4] = {__float2bfloat16(acc[i][jj][0]), __float2bfloat16(acc[i][jj][1]),
                     __float2bfloat16(acc[i][jj][2]), __float2bfloat16(acc[i][jj][3])};
        *(short4v*)(C2 + (size_t)v * MSZ + rowb) = *(short4v*)t;
      }
    }
    return;
  }

  // MODE 3: per-output-row invZ (rows = bm0+wm*64+i*16+q4*4+r)
  float iz[4][4];
  if (MODE == 3) {
#pragma unroll
    for (int i = 0; i < 4; i++)
#pragma unroll
      for (int r = 0; r < 4; r++)
        iz[i][r] = mz[(size_t)zb * 2048 + bm0 + wm * 64 + i * 16 + q4 * 4 + r].y;
  }

  CT* Cb = Cz;
  int coff = bn0;
  if (MODE == 1) {  // Q|K contiguous: K block sits MS*D after Q
    Cb = Cz + (bx >= 8 ? (size_t)MSZ * DD : 0);
    coff = (bx & 7) * BN;
  }
#pragma unroll
  for (int i = 0; i < 4; i++) {
#pragma unroll
    for (int jj = 0; jj < 4; jj++) {
#pragma unroll
      for (int r = 0; r < 4; r++) {
        const int row = bm0 + wm * 64 + i * 16 + q4 * 4 + r;
        const int col = coff + wn * 64 + jj * 16 + l15;
        float vv = acc[i][jj][r] * scale;
        if (MODE == 2 && by == bx && col > row) vv = -1e30f;  // pre-mask for PV exp
        if (MODE == 3) vv = acc[i][jj][r] * iz[i][r];
        cstore(&Cb[(size_t)row * ldc + col], vv);
      }
    }
  }
}

// Per-row softmax stats over the causal prefix: mz[b*S+q] = {rowmax, 1/sumexp}.
// Structure proven in softmax_rows (R8-R14); P write-back removed.
__global__ __launch_bounds__(256)
void row_stats(const bf16* __restrict__ Sc, float2* __restrict__ mz, int S) {
  const int q = blockIdx.x, b = blockIdx.y;
  const short8* srow = (const short8*)(Sc + ((size_t)b * S + q) * S);
  const int len = q + 1;
  const int tid = threadIdx.x;
  const int wave = tid >> 6, lane = tid & 63;
  __shared__ float red[10];

  const short8 raw = srow[tid];
  float v[8];
#pragma unroll
  for (int j = 0; j < 8; j++) {
    const int k = tid * 8 + j;
    const float f = __bfloat162float(((const bf16*)&raw)[j]);
    v[j] = (k < len) ? f : -1e30f;
  }

  float m = v[0];
#pragma unroll
  for (int j = 1; j < 8; j++) m = fmaxf(m, v[j]);
#pragma unroll
  for (int o = 32; o; o >>= 1) m = fmaxf(m, __shfl_down(m, o));
  if (lane == 0) red[wave] = m;
  __syncthreads();
  if (tid == 0) red[8] = fmaxf(fmaxf(red[0], red[1]), fmaxf(red[2], red[3]));
  __syncthreads();
  const float M = red[8];

  float s = 0.f;
#pragma unroll
  for (int j = 0; j < 8; j++) s += __expf(v[j] - M);
#pragma unroll
  for (int o = 32; o; o >>= 1) s += __shfl_down(s, o);
  if (lane == 0) red[4 + wave] = s;
  __syncthreads();
  if (tid == 0) {
    const float Z = red[4] + red[5] + red[6] + red[7];
    mz[(size_t)b * S + q] = make_float2(M, 1.f / Z);
  }
}

extern "C" void kernel_launch(void* const* d_in, const int* in_sizes, int n_in,
                              void* d_out, int out_size, void* d_ws, size_t ws_size,
                              hipStream_t stream) {
  const float* x  = (const float*)d_in[0];
  const float* Wq = (const float*)d_in[1];
  const float* Wk = (const float*)d_in[2];
  const float* Wv = (const float*)d_in[3];
  float* out = (float*)d_out;

  const int Bb = 4, S = 2048, D = 1024, MS = Bb * S;  // MS = 8192

  // ws layout (P buffer removed; mz after Sc)
  char* ws = (char*)d_ws;
  bf16* xb = (bf16*)ws;                                          // 16.78 MB
  bf16* wb = (bf16*)(ws + (size_t)MS * D * 2);                   // 6.3 MB
  bf16* Q  = (bf16*)(ws + (size_t)MS * D * 2 + 3u * D * D * 2);  // 16.78 MB
  bf16* Kp = Q + (size_t)MS * D;                                 // 16.78 MB (contig after Q)
  bf16* VT = Kp + (size_t)MS * D;                                // 16.78 MB [D,MS]
  bf16* Sc = VT + (size_t)MS * D;                                // 33.55 MB [B,S,S]
  float2* mz = (float2*)(Sc + (size_t)Bb * S * S);               // 64 KB {M, invZ}
  (void)Kp;

  dim3 blk(256);

  f2b<<<dim3(MS * D / 4 / 256), blk, 0, stream>>>(x, xb, MS * D);
  f2b3<<<dim3(D * D / 4 / 256, 3), blk, 0, stream>>>(Wq, Wk, Wv, wb, D * D);

  // QKV fused: [Q|K] rows + V transposed (1536 blocks, XCD-chunked decode)
  gemm_bt<1, bf16><<<dim3(1536), blk, 0, stream>>>(
      xb, wb, Q, VT, D, D, D, D, 0, 0, 0, 1.f);
  // Sc = (Q K^T)/32, triangular (544 blocks; diag tiles pre-masked -1e30)
  gemm_bt<2, bf16><<<dim3(544), blk, 0, stream>>>(
      Q, Kp, Sc, nullptr, D, D, S, D,
      (long)S * D, (long)S * D, (long)S * S, 0.03125f);
  // per-row {max, 1/sumexp}
  row_stats<<<dim3(S, Bb), blk, 0, stream>>>(Sc, mz, S);
  // out = exp(Sc - M) @ V * invZ  (512 blocks; A direct-from-global + inline exp)
  gemm_bt<3, float><<<dim3(512), blk, 0, stream>>>(
      Sc, VT, out, (bf16*)mz, S, MS, D, S,
      (long)S * S, (long)S, (long)S * D, 1.f);
}

// Round 10
// 292.320 us; speedup vs baseline: 1.2012x; 1.2012x over previous
//
#include <hip/hip_runtime.h>
#include <hip/hip_bf16.h>
#include <stdint.h>
#include <stddef.h>

// Causal single-head attention, B=4 S=2048 D=1024. fp32 in/out; bf16 MFMA inside.
// R17: back half fully reverted to R14 (best, 307.4us). QKV replaced by a
// faithful counted-vmcnt deep-pipeline kernel (qkv_8p):
//   256x128 tile, 8 waves (4Mx2N, 64x64 out each), BK=64, 2 phases/K-tile
//   split by k-slice (ks0,ks1) -- stage granularity == consumption order.
//   Double-buffered LDS (96KB): As[2][2048], Bs[2][1024], layout
//   [ks][rowblock][granule][row8] (lane-linear for global_load_lds).
//   Per phase: ds_read frags -> stage(t+1, ks) [3 insts/wave] ->
//   s_waitcnt vmcnt(3) -> s_barrier -> setprio(1) -> 16 MFMA -> setprio(0)
//   -> s_barrier. vmcnt(3) guarantees the slice staged 2 phases ago has
//   landed (counting proof in session notes); never drains to 0 in-loop.
// Sc/PV/softmax/f2b identical to R14 => their dispatch times are controls.

typedef __hip_bfloat16 bf16;
typedef short short8 __attribute__((ext_vector_type(8)));
typedef short short4v __attribute__((ext_vector_type(4)));
typedef float f32x4 __attribute__((ext_vector_type(4)));

#define BM 128
#define BN 128
#define BK 64
#define MSZ 8192   // B*S
#define DD 1024    // D

__device__ __forceinline__ void cstore(float* p, float v) { *p = v; }
__device__ __forceinline__ void cstore(bf16* p, float v) { *p = __float2bfloat16(v); }

// fp32 -> bf16 downcast, 4 elems/thread
__global__ __launch_bounds__(256)
void f2b(const float* __restrict__ s, bf16* __restrict__ d, int n) {
  const int i = (blockIdx.x * 256 + threadIdx.x) * 4;
  if (i >= n) return;
  const float4 v = *(const float4*)(s + i);
  bf16 t[4] = {__float2bfloat16(v.x), __float2bfloat16(v.y),
               __float2bfloat16(v.z), __float2bfloat16(v.w)};
  *(short4v*)(d + i) = *(short4v*)t;
}

// three weight matrices -> contiguous bf16 block [Wq;Wk;Wv]
__global__ __launch_bounds__(256)
void f2b3(const float* __restrict__ a, const float* __restrict__ b,
          const float* __restrict__ c, bf16* __restrict__ d, int n) {
  const float* s = (blockIdx.y == 0) ? a : (blockIdx.y == 1) ? b : c;
  const int i = (blockIdx.x * 256 + threadIdx.x) * 4;
  if (i >= n) return;
  const float4 v = *(const float4*)(s + i);
  bf16 t[4] = {__float2bfloat16(v.x), __float2bfloat16(v.y),
               __float2bfloat16(v.z), __float2bfloat16(v.w)};
  *(short4v*)(d + (size_t)blockIdx.y * n + i) = *(short4v*)t;
}

// ---------------- QKV: 256x128 deep-pipeline (R17) ----------------
// C = xb[8192,1024] * W_all[3072,1024]^T. Grid 768 = 8 XCD x 96.
// by = c*4 + (j&3) (A-band 2MB L2-resident per XCD), bx = j>>2 (0..23).
// bx<16 -> Q|K rows; bx>=16 -> V transposed into C2[D][MS].
__global__ __launch_bounds__(512, 1)
void qkv_8p(const bf16* __restrict__ A, const bf16* __restrict__ B,
            bf16* __restrict__ C, bf16* __restrict__ C2) {
  __shared__ short8 As[2][2048];  // 32KB/buf: [ks][rb 0..31][g 0..3][r8]
  __shared__ short8 Bs[2][1024];  // 16KB/buf: [ks][rb 0..15][g 0..3][r8]

  const int flat = blockIdx.x;
  const int c = flat & 7, j = flat >> 3;
  const int by = c * 4 + (j & 3), bx = j >> 2;
  const int bm0 = by * 256, bn0 = bx * 128;
  const int tid = threadIdx.x, wave = tid >> 6, lane = tid & 63;
  const int wm = wave >> 1, wn = wave & 1;  // 4x2 grid, 64x64 per wave
  const int l15 = lane & 15, q4 = lane >> 4;
  const int rh = l15 >> 3, r3 = l15 & 7;
  // staging lane decomposition: lane = (shb<<5)|(sgk<<3)|sr
  const int sr = lane & 7, sgk = (lane >> 3) & 3, shb = lane >> 5;

  const bf16* apg = A + (size_t)(bm0 + wave * 32 + shb * 8 + sr) * DD + sgk * 8;
  const bf16* bpg = B + (size_t)(bn0 + wave * 16 + shb * 8 + sr) * DD + sgk * 8;

  const int NT = DD / 64;  // 16 K-tiles

  // stage slice ks of tile t into buf t&1: A 2 insts + B 1 inst per wave
  auto stage = [&](int t, int ks) {
    const int b = t & 1;
    const size_t ko = (size_t)(t * 64 + ks * 32);
#pragma unroll
    for (int i = 0; i < 2; i++)
      __builtin_amdgcn_global_load_lds(apg + (size_t)(i * 16) * DD + ko,
                                       &As[b][ks * 1024 + wave * 128 + i * 64], 16, 0, 0);
    __builtin_amdgcn_global_load_lds(bpg + ko,
                                     &Bs[b][ks * 512 + wave * 64], 16, 0, 0);
  };

  // fragment bases: idx = ks*sz + (row>>3)*32 + q4*8 + (row&7)
  const int fa = wm * 256 + rh * 32 + q4 * 8 + r3;  // + ks*1024 + i*64
  const int fb = wn * 256 + rh * 32 + q4 * 8 + r3;  // + ks*512  + jj*64

  f32x4 acc[4][4] = {};

  // prologue: both slices of tile 0; vmcnt(3) -> ks0 resident
  stage(0, 0);
  stage(0, 1);
  asm volatile("s_waitcnt vmcnt(3)" ::: "memory");
  asm volatile("s_barrier" ::: "memory");

  for (int t = 0; t < NT; ++t) {
    const int b = t & 1;
#pragma unroll
    for (int ks = 0; ks < 2; ++ks) {
      short8 af[4], bfr[4];
#pragma unroll
      for (int i = 0; i < 4; i++) af[i] = As[b][ks * 1024 + fa + i * 64];
#pragma unroll
      for (int jj = 0; jj < 4; jj++) bfr[jj] = Bs[b][ks * 512 + fb + jj * 64];
      if (t + 1 < NT) {
        stage(t + 1, ks);  // lands 2 phases from now; consumed next tile
        asm volatile("s_waitcnt vmcnt(3)" ::: "memory");
      } else {
        asm volatile("s_waitcnt vmcnt(0)" ::: "memory");
      }
      asm volatile("s_barrier" ::: "memory");
      __builtin_amdgcn_s_setprio(1);
#pragma unroll
      for (int i = 0; i < 4; i++)
#pragma unroll
        for (int jj = 0; jj < 4; jj++)
          acc[i][jj] = __builtin_amdgcn_mfma_f32_16x16x32_bf16(af[i], bfr[jj], acc[i][jj], 0, 0, 0);
      __builtin_amdgcn_s_setprio(0);
      asm volatile("s_barrier" ::: "memory");
    }
  }

  // epilogue (C/D: col=lane&15, row=(lane>>4)*4+reg)
  if (bx >= 16) {
#pragma unroll
    for (int i = 0; i < 4; i++) {
#pragma unroll
      for (int jj = 0; jj < 4; jj++) {
        const int rowb = bm0 + wm * 64 + i * 16 + q4 * 4;
        const int v = (bn0 - 2048) + wn * 64 + jj * 16 + l15;
        bf16 t4[4] = {__float2bfloat16(acc[i][jj][0]), __float2bfloat16(acc[i][jj][1]),
                      __float2bfloat16(acc[i][jj][2]), __float2bfloat16(acc[i][jj][3])};
        *(short4v*)(C2 + (size_t)v * MSZ + rowb) = *(short4v*)t4;
      }
    }
    return;
  }
  bf16* Cb = C + (bx >= 8 ? (size_t)MSZ * DD : 0);
  const int coff = (bx & 7) * 128;
#pragma unroll
  for (int i = 0; i < 4; i++) {
#pragma unroll
    for (int jj = 0; jj < 4; jj++) {
#pragma unroll
      for (int r = 0; r < 4; r++) {
        const int row = bm0 + wm * 64 + i * 16 + q4 * 4 + r;
        const int col = coff + wn * 64 + jj * 16 + l15;
        Cb[(size_t)row * DD + col] = __float2bfloat16(acc[i][jj][r]);
      }
    }
  }
}
// ---------------- end QKV ----------------

// C[M,N] = A[M,K] * B[N,K]^T (both K-contiguous), bf16 in. Inner loop = R8/R14.
// MODE 2: Sc — triangular, XCD pair per batch.            544 blocks.
// MODE 3: PV — float out, K clipped at diagonal.          512 blocks.
template <int MODE, typename CT>
__global__ __launch_bounds__(256, 4)
void gemm_bt(const bf16* __restrict__ A, const bf16* __restrict__ B,
             CT* __restrict__ C, bf16* __restrict__ C2,
             int lda, int ldb, int ldc, int K,
             long sA, long sB, long sC, float scale) {
  int by, bx, zb;
  const int flat = blockIdx.x;
  const int c = flat & 7, j = flat >> 3;  // XCD (flat%8 round-robin)
  if (MODE == 2) {
    zb = c >> 1;
    const int t = (c & 1) * 68 + j;
    by = (int)((__fsqrt_rn(8.f * (float)t + 1.f) - 1.f) * 0.5f);
    while ((by + 1) * (by + 2) / 2 <= t) by++;
    while (by * (by + 1) / 2 > t) by--;
    bx = t - by * (by + 1) / 2;
  } else {
    zb = c >> 1;
    bx = j & 7;
    by = 2 * (7 - (j >> 3)) + (c & 1);
  }

  __shared__ short8 As[1024];  // 16 KB: [rb 0..15][g 0..7][r8 0..7]
  __shared__ short8 Bs[1024];  // 16 KB

  const int tid = threadIdx.x;
  const int wave = tid >> 6, lane = tid & 63;
  const int wm = wave >> 1, wn = wave & 1;  // 2x2 wave grid, 64x64 each
  const int l15 = lane & 15, q4 = lane >> 4;
  const int bm0 = by * BM, bn0 = bx * BN;

  const bf16* Az = A + (long)zb * sA;
  const bf16* Bz = B + (long)zb * sB;
  CT* Cz = C + (long)zb * sC;

  const int sg = lane >> 3, sr = lane & 7;
  const bf16* apg = Az + (size_t)(bm0 + wave * 32 + sr) * lda + sg * 8;
  const bf16* bpg = Bz + (size_t)(bn0 + wave * 32 + sr) * ldb + sg * 8;
  short8* asw = &As[wave * 256];
  short8* bsw = &Bs[wave * 256];

  const int Ke = (MODE == 3) ? min(K, (by + 1) * BM) : K;

  const int rh = l15 >> 3, r3 = l15 & 7;
  const int fra = wm * 512 + rh * 64 + q4 * 8 + r3;
  const int frb = wn * 512 + rh * 64 + q4 * 8 + r3;

  f32x4 acc[4][4] = {};

  for (int k0 = 0; k0 < Ke; k0 += BK) {
#pragma unroll
    for (int jj = 0; jj < 4; jj++) {
      __builtin_amdgcn_global_load_lds(apg + (size_t)jj * 8 * lda + k0,
                                       asw + jj * 64, 16, 0, 0);
      __builtin_amdgcn_global_load_lds(bpg + (size_t)jj * 8 * ldb + k0,
                                       bsw + jj * 64, 16, 0, 0);
    }
    __syncthreads();

#pragma unroll
    for (int s = 0; s < 2; s++) {
      short8 af[4], bfr[4];
#pragma unroll
      for (int i = 0; i < 4; i++) af[i] = As[fra + i * 128 + s * 32];
#pragma unroll
      for (int jj = 0; jj < 4; jj++) bfr[jj] = Bs[frb + jj * 128 + s * 32];
#pragma unroll
      for (int i = 0; i < 4; i++)
#pragma unroll
        for (int jj = 0; jj < 4; jj++)
          acc[i][jj] = __builtin_amdgcn_mfma_f32_16x16x32_bf16(af[i], bfr[jj], acc[i][jj], 0, 0, 0);
    }
    __syncthreads();
  }

#pragma unroll
  for (int i = 0; i < 4; i++) {
#pragma unroll
    for (int jj = 0; jj < 4; jj++) {
#pragma unroll
      for (int r = 0; r < 4; r++) {
        const int row = bm0 + wm * 64 + i * 16 + q4 * 4 + r;
        const int col = bn0 + wn * 64 + jj * 16 + l15;
        cstore(&Cz[(size_t)row * ldc + col], acc[i][jj][r] * scale);
      }
    }
  }
}

// Single-pass register softmax over the causal prefix; one 256-thr block per
// (q,b) row. Zeros above the diagonal so the PV GEMM needs no masking.
__global__ __launch_bounds__(256)
void softmax_rows(const bf16* __restrict__ Sc, bf16* __restrict__ P, int S) {
  const int q = blockIdx.x, b = blockIdx.y;
  const short8* srow = (const short8*)(Sc + ((size_t)b * S + q) * S);
  short8* prow = (short8*)(P + ((size_t)b * S + q) * S);
  const int len = q + 1;
  const int tid = threadIdx.x;
  const int wave = tid >> 6, lane = tid & 63;
  __shared__ float red[10];

  const short8 raw = srow[tid];
  float v[8];
#pragma unroll
  for (int j = 0; j < 8; j++) {
    const int k = tid * 8 + j;
    const float f = __bfloat162float(((const bf16*)&raw)[j]);
    v[j] = (k < len) ? f : -1e30f;
  }

  float m = v[0];
#pragma unroll
  for (int j = 1; j < 8; j++) m = fmaxf(m, v[j]);
#pragma unroll
  for (int o = 32; o; o >>= 1) m = fmaxf(m, __shfl_down(m, o));
  if (lane == 0) red[wave] = m;
  __syncthreads();
  if (tid == 0) red[8] = fmaxf(fmaxf(red[0], red[1]), fmaxf(red[2], red[3]));
  __syncthreads();
  const float M = red[8];

  float e[8], s = 0.f;
#pragma unroll
  for (int j = 0; j < 8; j++) { e[j] = __expf(v[j] - M); s += e[j]; }
#pragma unroll
  for (int o = 32; o; o >>= 1) s += __shfl_down(s, o);
  if (lane == 0) red[4 + wave] = s;
  __syncthreads();
  if (tid == 0) red[9] = red[4] + red[5] + red[6] + red[7];
  __syncthreads();
  const float inv = 1.f / red[9];

  short8 outp;
#pragma unroll
  for (int j = 0; j < 8; j++) {
    const int k = tid * 8 + j;
    ((bf16*)&outp)[j] = __float2bfloat16((k < len) ? e[j] * inv : 0.f);
  }
  prow[tid] = outp;
}

extern "C" void kernel_launch(void* const* d_in, const int* in_sizes, int n_in,
                              void* d_out, int out_size, void* d_ws, size_t ws_size,
                              hipStream_t stream) {
  const float* x  = (const float*)d_in[0];
  const float* Wq = (const float*)d_in[1];
  const float* Wk = (const float*)d_in[2];
  const float* Wv = (const float*)d_in[3];
  float* out = (float*)d_out;

  const int Bb = 4, S = 2048, D = 1024, MS = Bb * S;  // MS = 8192

  // ws layout; P aliases dead xb/W/Q region (consumed before softmax).
  char* ws = (char*)d_ws;
  bf16* xb = (bf16*)ws;                                          // 16.78 MB
  bf16* wb = (bf16*)(ws + (size_t)MS * D * 2);                   // 6.3 MB
  bf16* Q  = (bf16*)(ws + (size_t)MS * D * 2 + 3u * D * D * 2);  // 16.78 MB
  bf16* Kp = Q + (size_t)MS * D;                                 // 16.78 MB (contig after Q)
  bf16* VT = Kp + (size_t)MS * D;                                // 16.78 MB [D,MS]
  bf16* Sc = VT + (size_t)MS * D;                                // 33.55 MB [B,S,S]
  bf16* P  = (bf16*)ws;                                          // aliases xb/W/Q
  (void)Kp;

  dim3 blk(256);

  f2b<<<dim3(MS * D / 4 / 256), blk, 0, stream>>>(x, xb, MS * D);
  f2b3<<<dim3(D * D / 4 / 256, 3), blk, 0, stream>>>(Wq, Wk, Wv, wb, D * D);

  // QKV fused: deep-pipeline 256x128 kernel (768 blocks x 512 thr)
  qkv_8p<<<dim3(768), dim3(512), 0, stream>>>(xb, wb, Q, VT);
  // Sc = (Q K^T)/32, triangular (544 blocks: XCD pair per batch)
  gemm_bt<2, bf16><<<dim3(544), blk, 0, stream>>>(
      Q, Kp, Sc, nullptr, D, D, S, D,
      (long)S * D, (long)S * D, (long)S * S, 0.03125f);
  // P = row-softmax(Sc)
  softmax_rows<<<dim3(S, Bb), blk, 0, stream>>>(Sc, P, S);
  // out = P @ V  (512 blocks: XCD pair per batch, K clipped at diagonal)
  gemm_bt<3, float><<<dim3(512), blk, 0, stream>>>(
      P, VT, out, nullptr, S, MS, D, S,
      (long)S * S, (long)S, (long)S * D, 1.f);
}

// Round 11
// 285.225 us; speedup vs baseline: 1.2311x; 1.0249x over previous
//
#include <hip/hip_runtime.h>
#include <hip/hip_bf16.h>
#include <stdint.h>
#include <stddef.h>

// Causal single-head attention, B=4 S=2048 D=1024. fp32 in/out; bf16 MFMA inside.
// R18: deep pipeline (counted-vmcnt, stage-by-consumption-slice) ported from
// qkv_8p (R17: 107->89us, +21% rate) to Sc and PV:
//   sc_dp: 256x128 8-wave dbuf, tri decode at BM=256 (288 blocks, XCD-pair
//          per batch), vmcnt(3)/phase, never 0 in-loop.
//   pv_dp: 128x128 4-wave dbuf, R14's balanced parity-desc 512-block grid,
//          4 stage-insts/phase -> vmcnt(4)/phase.
// qkv_8p, f2b/f2b3, softmax byte-identical to R17 (controls).

typedef __hip_bfloat16 bf16;
typedef short short8 __attribute__((ext_vector_type(8)));
typedef short short4v __attribute__((ext_vector_type(4)));
typedef float f32x4 __attribute__((ext_vector_type(4)));

#define MSZ 8192   // B*S
#define DD 1024    // D
#define SS 2048    // S

__global__ __launch_bounds__(256)
void f2b(const float* __restrict__ s, bf16* __restrict__ d, int n) {
  const int i = (blockIdx.x * 256 + threadIdx.x) * 4;
  if (i >= n) return;
  const float4 v = *(const float4*)(s + i);
  bf16 t[4] = {__float2bfloat16(v.x), __float2bfloat16(v.y),
               __float2bfloat16(v.z), __float2bfloat16(v.w)};
  *(short4v*)(d + i) = *(short4v*)t;
}

__global__ __launch_bounds__(256)
void f2b3(const float* __restrict__ a, const float* __restrict__ b,
          const float* __restrict__ c, bf16* __restrict__ d, int n) {
  const float* s = (blockIdx.y == 0) ? a : (blockIdx.y == 1) ? b : c;
  const int i = (blockIdx.x * 256 + threadIdx.x) * 4;
  if (i >= n) return;
  const float4 v = *(const float4*)(s + i);
  bf16 t[4] = {__float2bfloat16(v.x), __float2bfloat16(v.y),
               __float2bfloat16(v.z), __float2bfloat16(v.w)};
  *(short4v*)(d + (size_t)blockIdx.y * n + i) = *(short4v*)t;
}

// ---------------- QKV: 256x128 deep-pipeline (verbatim R17) ----------------
__global__ __launch_bounds__(512, 1)
void qkv_8p(const bf16* __restrict__ A, const bf16* __restrict__ B,
            bf16* __restrict__ C, bf16* __restrict__ C2) {
  __shared__ short8 As[2][2048];
  __shared__ short8 Bs[2][1024];

  const int flat = blockIdx.x;
  const int c = flat & 7, j = flat >> 3;
  const int by = c * 4 + (j & 3), bx = j >> 2;
  const int bm0 = by * 256, bn0 = bx * 128;
  const int tid = threadIdx.x, wave = tid >> 6, lane = tid & 63;
  const int wm = wave >> 1, wn = wave & 1;
  const int l15 = lane & 15, q4 = lane >> 4;
  const int rh = l15 >> 3, r3 = l15 & 7;
  const int sr = lane & 7, sgk = (lane >> 3) & 3, shb = lane >> 5;

  const bf16* apg = A + (size_t)(bm0 + wave * 32 + shb * 8 + sr) * DD + sgk * 8;
  const bf16* bpg = B + (size_t)(bn0 + wave * 16 + shb * 8 + sr) * DD + sgk * 8;

  const int NT = DD / 64;

  auto stage = [&](int t, int ks) {
    const int b = t & 1;
    const size_t ko = (size_t)(t * 64 + ks * 32);
#pragma unroll
    for (int i = 0; i < 2; i++)
      __builtin_amdgcn_global_load_lds(apg + (size_t)(i * 16) * DD + ko,
                                       &As[b][ks * 1024 + wave * 128 + i * 64], 16, 0, 0);
    __builtin_amdgcn_global_load_lds(bpg + ko,
                                     &Bs[b][ks * 512 + wave * 64], 16, 0, 0);
  };

  const int fa = wm * 256 + rh * 32 + q4 * 8 + r3;
  const int fb = wn * 256 + rh * 32 + q4 * 8 + r3;

  f32x4 acc[4][4] = {};

  stage(0, 0);
  stage(0, 1);
  asm volatile("s_waitcnt vmcnt(3)" ::: "memory");
  asm volatile("s_barrier" ::: "memory");

  for (int t = 0; t < NT; ++t) {
    const int b = t & 1;
#pragma unroll
    for (int ks = 0; ks < 2; ++ks) {
      short8 af[4], bfr[4];
#pragma unroll
      for (int i = 0; i < 4; i++) af[i] = As[b][ks * 1024 + fa + i * 64];
#pragma unroll
      for (int jj = 0; jj < 4; jj++) bfr[jj] = Bs[b][ks * 512 + fb + jj * 64];
      if (t + 1 < NT) {
        stage(t + 1, ks);
        asm volatile("s_waitcnt vmcnt(3)" ::: "memory");
      } else {
        asm volatile("s_waitcnt vmcnt(0)" ::: "memory");
      }
      asm volatile("s_barrier" ::: "memory");
      __builtin_amdgcn_s_setprio(1);
#pragma unroll
      for (int i = 0; i < 4; i++)
#pragma unroll
        for (int jj = 0; jj < 4; jj++)
          acc[i][jj] = __builtin_amdgcn_mfma_f32_16x16x32_bf16(af[i], bfr[jj], acc[i][jj], 0, 0, 0);
      __builtin_amdgcn_s_setprio(0);
      asm volatile("s_barrier" ::: "memory");
    }
  }

  if (bx >= 16) {
#pragma unroll
    for (int i = 0; i < 4; i++) {
#pragma unroll
      for (int jj = 0; jj < 4; jj++) {
        const int rowb = bm0 + wm * 64 + i * 16 + q4 * 4;
        const int v = (bn0 - 2048) + wn * 64 + jj * 16 + l15;
        bf16 t4[4] = {__float2bfloat16(acc[i][jj][0]), __float2bfloat16(acc[i][jj][1]),
                      __float2bfloat16(acc[i][jj][2]), __float2bfloat16(acc[i][jj][3])};
        *(short4v*)(C2 + (size_t)v * MSZ + rowb) = *(short4v*)t4;
      }
    }
    return;
  }
  bf16* Cb = C + (bx >= 8 ? (size_t)MSZ * DD : 0);
  const int coff = (bx & 7) * 128;
#pragma unroll
  for (int i = 0; i < 4; i++) {
#pragma unroll
    for (int jj = 0; jj < 4; jj++) {
#pragma unroll
      for (int r = 0; r < 4; r++) {
        const int row = bm0 + wm * 64 + i * 16 + q4 * 4 + r;
        const int col = coff + wn * 64 + jj * 16 + l15;
        Cb[(size_t)row * DD + col] = __float2bfloat16(acc[i][jj][r]);
      }
    }
  }
}

// ---------------- Sc: 256x128 deep-pipeline, triangular ----------------
// Sc[zb] = (Q[zb] K[zb]^T)/32. 288 blocks = 8 XCD x 36; XCD pair owns batch;
// halves split tri range t in 0..71: cum(by)=by^2+by, bx = t - cum, bx<=2by+1.
__global__ __launch_bounds__(512, 1)
void sc_dp(const bf16* __restrict__ Q, const bf16* __restrict__ Kp,
           bf16* __restrict__ Sc) {
  __shared__ short8 As[2][2048];
  __shared__ short8 Bs[2][1024];

  const int flat = blockIdx.x;
  const int c = flat & 7;
  const int zb = c >> 1;
  const int t = (c & 1) * 36 + (flat >> 3);
  int by = (int)((__fsqrt_rn(4.f * (float)t + 1.f) - 1.f) * 0.5f);
  while ((by + 1) * (by + 2) <= t) by++;
  while (by * (by + 1) > t) by--;
  const int bx = t - by * (by + 1);

  const int bm0 = by * 256, bn0 = bx * 128;
  const int tid = threadIdx.x, wave = tid >> 6, lane = tid & 63;
  const int wm = wave >> 1, wn = wave & 1;
  const int l15 = lane & 15, q4 = lane >> 4;
  const int rh = l15 >> 3, r3 = l15 & 7;
  const int sr = lane & 7, sgk = (lane >> 3) & 3, shb = lane >> 5;

  const bf16* Az = Q + (size_t)zb * SS * DD;
  const bf16* Bz = Kp + (size_t)zb * SS * DD;
  const bf16* apg = Az + (size_t)(bm0 + wave * 32 + shb * 8 + sr) * DD + sgk * 8;
  const bf16* bpg = Bz + (size_t)(bn0 + wave * 16 + shb * 8 + sr) * DD + sgk * 8;

  const int NT = DD / 64;

  auto stage = [&](int tt, int ks) {
    const int b = tt & 1;
    const size_t ko = (size_t)(tt * 64 + ks * 32);
#pragma unroll
    for (int i = 0; i < 2; i++)
      __builtin_amdgcn_global_load_lds(apg + (size_t)(i * 16) * DD + ko,
                                       &As[b][ks * 1024 + wave * 128 + i * 64], 16, 0, 0);
    __builtin_amdgcn_global_load_lds(bpg + ko,
                                     &Bs[b][ks * 512 + wave * 64], 16, 0, 0);
  };

  const int fa = wm * 256 + rh * 32 + q4 * 8 + r3;
  const int fb = wn * 256 + rh * 32 + q4 * 8 + r3;

  f32x4 acc[4][4] = {};

  stage(0, 0);
  stage(0, 1);
  asm volatile("s_waitcnt vmcnt(3)" ::: "memory");
  asm volatile("s_barrier" ::: "memory");

  for (int tt = 0; tt < NT; ++tt) {
    const int b = tt & 1;
#pragma unroll
    for (int ks = 0; ks < 2; ++ks) {
      short8 af[4], bfr[4];
#pragma unroll
      for (int i = 0; i < 4; i++) af[i] = As[b][ks * 1024 + fa + i * 64];
#pragma unroll
      for (int jj = 0; jj < 4; jj++) bfr[jj] = Bs[b][ks * 512 + fb + jj * 64];
      if (tt + 1 < NT) {
        stage(tt + 1, ks);
        asm volatile("s_waitcnt vmcnt(3)" ::: "memory");
      } else {
        asm volatile("s_waitcnt vmcnt(0)" ::: "memory");
      }
      asm volatile("s_barrier" ::: "memory");
      __builtin_amdgcn_s_setprio(1);
#pragma unroll
      for (int i = 0; i < 4; i++)
#pragma unroll
        for (int jj = 0; jj < 4; jj++)
          acc[i][jj] = __builtin_amdgcn_mfma_f32_16x16x32_bf16(af[i], bfr[jj], acc[i][jj], 0, 0, 0);
      __builtin_amdgcn_s_setprio(0);
      asm volatile("s_barrier" ::: "memory");
    }
  }

  bf16* Cz = Sc + (size_t)zb * SS * SS;
#pragma unroll
  for (int i = 0; i < 4; i++) {
#pragma unroll
    for (int jj = 0; jj < 4; jj++) {
#pragma unroll
      for (int r = 0; r < 4; r++) {
        const int row = bm0 + wm * 64 + i * 16 + q4 * 4 + r;
        const int col = bn0 + wn * 64 + jj * 16 + l15;
        Cz[(size_t)row * SS + col] = __float2bfloat16(acc[i][jj][r] * 0.03125f);
      }
    }
  }
}

// ---------------- PV: 128x128 deep-pipeline ----------------
// out[zb] = P[zb] @ VT[.,zb]. 512 blocks = 8 XCD x 64; XCD pair owns batch;
// bx = j&7 (VT panel shared), by = 2*(7-(j>>3)) + (c&1) (long-K first).
// K clipped at diagonal: Ke = min(2048, (by+1)*128), NT = Ke/64 >= 2.
__global__ __launch_bounds__(256, 2)
void pv_dp(const bf16* __restrict__ P, const bf16* __restrict__ VT,
           float* __restrict__ out) {
  __shared__ short8 As[2][1024];
  __shared__ short8 Bs[2][1024];

  const int flat = blockIdx.x;
  const int c = flat & 7, j = flat >> 3;
  const int zb = c >> 1;
  const int bx = j & 7;
  const int by = 2 * (7 - (j >> 3)) + (c & 1);

  const int bm0 = by * 128, bn0 = bx * 128;
  const int tid = threadIdx.x, wave = tid >> 6, lane = tid & 63;
  const int wm = wave >> 1, wn = wave & 1;
  const int l15 = lane & 15, q4 = lane >> 4;
  const int rh = l15 >> 3, r3 = l15 & 7;
  const int sr = lane & 7, sgk = (lane >> 3) & 3, shb = lane >> 5;

  const bf16* Az = P + (size_t)zb * SS * SS;
  const bf16* Bz = VT + (size_t)zb * SS;  // batch slice of [D][MS]
  const bf16* apg = Az + (size_t)(bm0 + wave * 32 + shb * 8 + sr) * SS + sgk * 8;
  const bf16* bpg = Bz + (size_t)(bn0 + wave * 32 + shb * 8 + sr) * MSZ + sgk * 8;

  const int Ke = min(SS, (by + 1) * 128);
  const int NT = Ke >> 6;

  // stage slice ks of tile t: A 2 insts + B 2 insts per wave (4 total)
  auto stage = [&](int t, int ks) {
    const int b = t & 1;
    const size_t ko = (size_t)(t * 64 + ks * 32);
#pragma unroll
    for (int i = 0; i < 2; i++) {
      __builtin_amdgcn_global_load_lds(apg + (size_t)(i * 16) * SS + ko,
                                       &As[b][ks * 512 + wave * 128 + i * 64], 16, 0, 0);
      __builtin_amdgcn_global_load_lds(bpg + (size_t)(i * 16) * MSZ + ko,
                                       &Bs[b][ks * 512 + wave * 128 + i * 64], 16, 0, 0);
    }
  };

  // fragment bases: row = wm|wn *64 + idx*16 + l15; rb = row>>3
  const int fa = wm * 256 + rh * 32 + q4 * 8 + r3;  // + ks*512 + i*64
  const int fb = wn * 256 + rh * 32 + q4 * 8 + r3;

  f32x4 acc[4][4] = {};

  stage(0, 0);
  stage(0, 1);
  asm volatile("s_waitcnt vmcnt(4)" ::: "memory");
  asm volatile("s_barrier" ::: "memory");

  for (int t = 0; t < NT; ++t) {
    const int b = t & 1;
#pragma unroll
    for (int ks = 0; ks < 2; ++ks) {
      short8 af[4], bfr[4];
#pragma unroll
      for (int i = 0; i < 4; i++) af[i] = As[b][ks * 512 + fa + i * 64];
#pragma unroll
      for (int jj = 0; jj < 4; jj++) bfr[jj] = Bs[b][ks * 512 + fb + jj * 64];
      if (t + 1 < NT) {
        stage(t + 1, ks);
        asm volatile("s_waitcnt vmcnt(4)" ::: "memory");
      } else {
        asm volatile("s_waitcnt vmcnt(0)" ::: "memory");
      }
      asm volatile("s_barrier" ::: "memory");
      __builtin_amdgcn_s_setprio(1);
#pragma unroll
      for (int i = 0; i < 4; i++)
#pragma unroll
        for (int jj = 0; jj < 4; jj++)
          acc[i][jj] = __builtin_amdgcn_mfma_f32_16x16x32_bf16(af[i], bfr[jj], acc[i][jj], 0, 0, 0);
      __builtin_amdgcn_s_setprio(0);
      asm volatile("s_barrier" ::: "memory");
    }
  }

  float* Cz = out + (size_t)zb * SS * DD;
#pragma unroll
  for (int i = 0; i < 4; i++) {
#pragma unroll
    for (int jj = 0; jj < 4; jj++) {
#pragma unroll
      for (int r = 0; r < 4; r++) {
        const int row = bm0 + wm * 64 + i * 16 + q4 * 4 + r;
        const int col = bn0 + wn * 64 + jj * 16 + l15;
        Cz[(size_t)row * DD + col] = acc[i][jj][r];
      }
    }
  }
}

// Single-pass register softmax over the causal prefix (verbatim R14).
__global__ __launch_bounds__(256)
void softmax_rows(const bf16* __restrict__ Sc, bf16* __restrict__ P, int S) {
  const int q = blockIdx.x, b = blockIdx.y;
  const short8* srow = (const short8*)(Sc + ((size_t)b * S + q) * S);
  short8* prow = (short8*)(P + ((size_t)b * S + q) * S);
  const int len = q + 1;
  const int tid = threadIdx.x;
  const int wave = tid >> 6, lane = tid & 63;
  __shared__ float red[10];

  const short8 raw = srow[tid];
  float v[8];
#pragma unroll
  for (int j = 0; j < 8; j++) {
    const int k = tid * 8 + j;
    const float f = __bfloat162float(((const bf16*)&raw)[j]);
    v[j] = (k < len) ? f : -1e30f;
  }

  float m = v[0];
#pragma unroll
  for (int j = 1; j < 8; j++) m = fmaxf(m, v[j]);
#pragma unroll
  for (int o = 32; o; o >>= 1) m = fmaxf(m, __shfl_down(m, o));
  if (lane == 0) red[wave] = m;
  __syncthreads();
  if (tid == 0) red[8] = fmaxf(fmaxf(red[0], red[1]), fmaxf(red[2], red[3]));
  __syncthreads();
  const float M = red[8];

  float e[8], s = 0.f;
#pragma unroll
  for (int j = 0; j < 8; j++) { e[j] = __expf(v[j] - M); s += e[j]; }
#pragma unroll
  for (int o = 32; o; o >>= 1) s += __shfl_down(s, o);
  if (lane == 0) red[4 + wave] = s;
  __syncthreads();
  if (tid == 0) red[9] = red[4] + red[5] + red[6] + red[7];
  __syncthreads();
  const float inv = 1.f / red[9];

  short8 outp;
#pragma unroll
  for (int j = 0; j < 8; j++) {
    const int k = tid * 8 + j;
    ((bf16*)&outp)[j] = __float2bfloat16((k < len) ? e[j] * inv : 0.f);
  }
  prow[tid] = outp;
}

extern "C" void kernel_launch(void* const* d_in, const int* in_sizes, int n_in,
                              void* d_out, int out_size, void* d_ws, size_t ws_size,
                              hipStream_t stream) {
  const float* x  = (const float*)d_in[0];
  const float* Wq = (const float*)d_in[1];
  const float* Wk = (const float*)d_in[2];
  const float* Wv = (const float*)d_in[3];
  float* out = (float*)d_out;

  const int Bb = 4, S = 2048, D = 1024, MS = Bb * S;  // MS = 8192

  // ws layout; P aliases dead xb/W/Q region (consumed before softmax).
  char* ws = (char*)d_ws;
  bf16* xb = (bf16*)ws;                                          // 16.78 MB
  bf16* wb = (bf16*)(ws + (size_t)MS * D * 2);                   // 6.3 MB
  bf16* Q  = (bf16*)(ws + (size_t)MS * D * 2 + 3u * D * D * 2);  // 16.78 MB
  bf16* Kp = Q + (size_t)MS * D;                                 // 16.78 MB (contig after Q)
  bf16* VT = Kp + (size_t)MS * D;                                // 16.78 MB [D,MS]
  bf16* Sc = VT + (size_t)MS * D;                                // 33.55 MB [B,S,S]
  bf16* P  = (bf16*)ws;                                          // aliases xb/W/Q
  (void)Kp;

  dim3 blk(256);

  f2b<<<dim3(MS * D / 4 / 256), blk, 0, stream>>>(x, xb, MS * D);
  f2b3<<<dim3(D * D / 4 / 256, 3), blk, 0, stream>>>(Wq, Wk, Wv, wb, D * D);

  // QKV fused: deep-pipeline 256x128 (768 blocks x 512 thr)
  qkv_8p<<<dim3(768), dim3(512), 0, stream>>>(xb, wb, Q, VT);
  // Sc = (Q K^T)/32: deep-pipeline triangular (288 blocks x 512 thr)
  sc_dp<<<dim3(288), dim3(512), 0, stream>>>(Q, Kp, Sc);
  // P = row-softmax(Sc)
  softmax_rows<<<dim3(S, Bb), blk, 0, stream>>>(Sc, P, S);
  // out = P @ V: deep-pipeline (512 blocks x 256 thr)
  pv_dp<<<dim3(512), blk, 0, stream>>>(P, VT, out);
}